// Round 1
// baseline (266.049 us; speedup 1.0000x reference)
//
#include <hip/hip_runtime.h>
#include <stdint.h>

typedef unsigned short u16;
typedef __attribute__((ext_vector_type(8))) short short8;
typedef __attribute__((ext_vector_type(4))) short short4v;
typedef __attribute__((ext_vector_type(4))) float floatx4;

#define AS_GLOBAL __attribute__((address_space(1)))
#define AS_LDS    __attribute__((address_space(3)))

// exp2 argument scale folded into Qp: 1/sqrt(1024) * log2(e)
#define QSCALE 0.045084220f

__device__ __forceinline__ float bf2f(u16 u) {
  union { unsigned int i; float f; } x; x.i = ((unsigned int)u) << 16; return x.f;
}
__device__ __forceinline__ u16 f2bf(float f) {          // RNE
  union { float f; unsigned int i; } x; x.f = f;
  unsigned int u = x.i;
  u += 0x7fffu + ((u >> 16) & 1u);
  return (u16)(u >> 16);
}
__device__ __forceinline__ u16 f2bf_fast(float f) {     // round-half-up, 2 ops
  union { float f; unsigned int i; } x; x.f = f;
  return (u16)((x.i + 0x8000u) >> 16);
}

// Runtime dtype probe (R4-validated).
__device__ __forceinline__ int probe_is_f32(const void* p) {
  const unsigned int* w = (const unsigned int*)p;
  int cnt = 0;
#pragma unroll
  for (int i = 0; i < 64; ++i) {
    unsigned int lo = w[i] & 0xFFFFu;
    int e = (int)((lo >> 7) & 0xFFu);
    cnt += (e >= 117 && e <= 137) ? 1 : 0;
  }
  return cnt < 32;
}

__device__ __forceinline__ short8 ld8(const void* P, size_t off, int isf32) {
  if (isf32) {
    const float* q = (const float*)P + off;
    float4 x = *(const float4*)q;
    float4 y = *(const float4*)(q + 4);
    short8 r;
    r[0] = (short)f2bf(x.x); r[1] = (short)f2bf(x.y);
    r[2] = (short)f2bf(x.z); r[3] = (short)f2bf(x.w);
    r[4] = (short)f2bf(y.x); r[5] = (short)f2bf(y.y);
    r[6] = (short)f2bf(y.z); r[7] = (short)f2bf(y.w);
    return r;
  }
  return *(const short8*)((const u16*)P + off);
}

__device__ __forceinline__ float ldscalar(const void* P, size_t idx, int isf32) {
  return isf32 ? ((const float*)P)[idx] : bf2f(((const u16*)P)[idx]);
}

// ---------------------------------------------------------------------------
// cvt7: one-shot fp32->bf16 of 3 X tensors + 4 W tensors. grid (1024, 7).
// ---------------------------------------------------------------------------
__global__ __launch_bounds__(256) void cvt7(
    const void* s0, const void* s1, const void* s2, const void* s3,
    const void* s4, const void* s5, const void* s6,
    u16* d0, u16* d1, u16* d2, u16* d3, u16* d4, u16* d5, u16* d6)
{
  const int z = blockIdx.y;
  const void* src; u16* dst; int n;
  switch (z) {
    case 0: src = s0; dst = d0; n = 4194304; break;
    case 1: src = s1; dst = d1; n = 4194304; break;
    case 2: src = s2; dst = d2; n = 4194304; break;
    case 3: src = s3; dst = d3; n = 1048576; break;
    case 4: src = s4; dst = d4; n = 1048576; break;
    case 5: src = s5; dst = d5; n = 1048576; break;
    default: src = s6; dst = d6; n = 1048576; break;
  }
  const int isf32 = probe_is_f32(src);
  for (int i = blockIdx.x * 256 + threadIdx.x; i * 4 < n; i += gridDim.x * 256) {
    if (isf32) {
      float4 x = ((const float4*)src)[i];
      short4v r;
      r[0] = (short)f2bf(x.x); r[1] = (short)f2bf(x.y);
      r[2] = (short)f2bf(x.z); r[3] = (short)f2bf(x.w);
      *(short4v*)(dst + (size_t)i * 4) = r;
    } else {
      *(short4v*)(dst + (size_t)i * 4) = ((const short4v*)src)[i];
    }
  }
}

// ---------------------------------------------------------------------------
// bf16 MFMA GEMM core v3: BK=32 + DOUBLE-BUFFERED LDS with raw-asm barriers.
// Prefetch for tile k+1 is issued BEFORE the barrier and stays in flight
// across it (s_waitcnt vmcnt(4), never 0 inside the loop) — the AITER/
// hipBLASLt pattern the __syncthreads() structure cannot express.
// As/Bs must each be 8192 u16 (two 4096 buffers). 128x128 tile, 4 waves.
// ---------------------------------------------------------------------------
__device__ __forceinline__ void gemm_core_bf16(
    const u16* __restrict__ A, const u16* __restrict__ W,
    u16* As, u16* Bs, floatx4 acc[4][4], int m0, int n0, int K, int tid)
{
  const int lane = tid & 63, wv = tid >> 6;
  const int wm = wv >> 1, wn = wv & 1;
  const int g = lane >> 4, ml = lane & 15;
  const int r0 = tid >> 2, kc = (tid & 3) << 3;
  const u16* Ag0 = A + (size_t)(m0 + r0) * K + kc;
  const u16* Ag1 = A + (size_t)(m0 + r0 + 64) * K + kc;
  const u16* Bg0 = W + (size_t)(n0 + r0) * K + kc;
  const u16* Bg1 = W + (size_t)(n0 + r0 + 64) * K + kc;

#define STAGE_QKV(buf_, kt_) do {                                              \
    u16* a0 = As + (buf_) * 4096 + tid * 8;                                    \
    u16* b0 = Bs + (buf_) * 4096 + tid * 8;                                    \
    __builtin_amdgcn_global_load_lds((const AS_GLOBAL unsigned int*)(Ag0 + (kt_)), \
                                     (AS_LDS unsigned int*)a0, 16, 0, 0);      \
    __builtin_amdgcn_global_load_lds((const AS_GLOBAL unsigned int*)(Ag1 + (kt_)), \
                                     (AS_LDS unsigned int*)(a0 + 2048), 16, 0, 0); \
    __builtin_amdgcn_global_load_lds((const AS_GLOBAL unsigned int*)(Bg0 + (kt_)), \
                                     (AS_LDS unsigned int*)b0, 16, 0, 0);      \
    __builtin_amdgcn_global_load_lds((const AS_GLOBAL unsigned int*)(Bg1 + (kt_)), \
                                     (AS_LDS unsigned int*)(b0 + 2048), 16, 0, 0); \
  } while (0)

  STAGE_QKV(0, 0);
  int buf = 0;
#pragma unroll 2
  for (int kt = 0; kt < K; kt += 32) {
    const int nk = (kt + 32 < K) ? (kt + 32) : 0;   // dummy reload on last iter
    STAGE_QKV(buf ^ 1, nk);
    // wait current tile (4 oldest), keep prefetch (4 newest) in flight
    __asm__ __volatile__("s_waitcnt vmcnt(4)\n\ts_barrier" ::: "memory");
    const u16* Ac = As + buf * 4096;
    const u16* Bc = Bs + buf * 4096;
    short8 af[4], bf[4];
#pragma unroll
    for (int i = 0; i < 4; ++i)
      af[i] = *(const short8*)(Ac + (wm * 64 + i * 16 + ml) * 32 + g * 8);
#pragma unroll
    for (int j = 0; j < 4; ++j)
      bf[j] = *(const short8*)(Bc + (wn * 64 + j * 16 + ml) * 32 + g * 8);
#pragma unroll
    for (int i = 0; i < 4; ++i)
#pragma unroll
      for (int j = 0; j < 4; ++j)
        acc[i][j] = __builtin_amdgcn_mfma_f32_16x16x32_bf16(af[i], bf[j], acc[i][j], 0, 0, 0);
    // all waves done reading buf before it becomes next prefetch target
    __asm__ __volatile__("s_waitcnt lgkmcnt(0)\n\ts_barrier" ::: "memory");
    buf ^= 1;
  }
#undef STAGE_QKV
  // drain dummy prefetch before epilogue / endpgm (LDS-dealloc hazard)
  __asm__ __volatile__("s_waitcnt vmcnt(0)" ::: "memory");
}

// R7-proven fallback core: BK=32, cvt-in-staging. (As/Bs = 4096 u16)
__device__ __forceinline__ void gemm_core_cvt(
    const void* __restrict__ A, const void* __restrict__ W, int aF32, int bF32,
    u16* As, u16* Bs, floatx4 acc[4][4], int m0, int n0, int K, int tid)
{
  const int lane = tid & 63, wv = tid >> 6;
  const int wm = wv >> 1, wn = wv & 1;
  const int g = lane >> 4, ml = lane & 15;
  const int r0 = tid >> 2, kc = (tid & 3) << 3;
  const size_t offA0 = (size_t)(m0 + r0) * K + kc;
  const size_t offA1 = (size_t)(m0 + r0 + 64) * K + kc;
  const size_t offB0 = (size_t)(n0 + r0) * K + kc;
  const size_t offB1 = (size_t)(n0 + r0 + 64) * K + kc;
  u16* Al0 = As + tid * 8;  u16* Al1 = As + (tid + 256) * 8;
  u16* Bl0 = Bs + tid * 8;  u16* Bl1 = Bs + (tid + 256) * 8;
  for (int kt = 0; kt < K; kt += 32) {
    short8 a0 = ld8(A, offA0 + kt, aF32);
    short8 a1 = ld8(A, offA1 + kt, aF32);
    short8 b0 = ld8(W, offB0 + kt, bF32);
    short8 b1 = ld8(W, offB1 + kt, bF32);
    *(short8*)Al0 = a0;  *(short8*)Al1 = a1;
    *(short8*)Bl0 = b0;  *(short8*)Bl1 = b1;
    __syncthreads();
    short8 af[4], bf[4];
#pragma unroll
    for (int i = 0; i < 4; ++i)
      af[i] = *(const short8*)(As + (wm * 64 + i * 16 + ml) * 32 + g * 8);
#pragma unroll
    for (int j = 0; j < 4; ++j)
      bf[j] = *(const short8*)(Bs + (wn * 64 + j * 16 + ml) * 32 + g * 8);
#pragma unroll
    for (int i = 0; i < 4; ++i)
#pragma unroll
      for (int j = 0; j < 4; ++j)
        acc[i][j] = __builtin_amdgcn_mfma_f32_16x16x32_bf16(af[i], bf[j], acc[i][j], 0, 0, 0);
    __syncthreads();
  }
}

// ---------------------------------------------------------------------------
// QKV epilogue: z=0 (Q) scaled by QSCALE into [B,H,S,D]; z=1 (K) [B,H,S,D];
// z=2 (V) TRANSPOSED into [B,H,D,S] (4-wide packed along s).
// ---------------------------------------------------------------------------
__device__ __forceinline__ void qkv_epilogue(
    floatx4 acc[4][4], const void* Bi, int cF32, u16* O, int m0, int n0,
    int tid, int z)
{
  const int lane = tid & 63, wv = tid >> 6;
  const int wm = wv >> 1, wn = wv & 1, g = lane >> 4, ml = lane & 15;
  const float sc = (z == 0) ? QSCALE : 1.0f;
#pragma unroll
  for (int j = 0; j < 4; ++j) {
    int gn = n0 + wn * 64 + j * 16 + ml;
    float bvv = ldscalar(Bi, (size_t)gn, cF32);
    int h = gn >> 6, d = gn & 63;
    if (z == 2) {
#pragma unroll
      for (int i = 0; i < 4; ++i) {
        int gm0 = m0 + wm * 64 + i * 16 + g * 4;
        int b = gm0 >> 11, s0 = gm0 & 2047;
        short4v pk;
#pragma unroll
        for (int r = 0; r < 4; ++r) pk[r] = (short)f2bf_fast(acc[i][j][r] + bvv);
        *(short4v*)(O + ((((size_t)b * 16 + h) * 64 + d) * 2048 + s0)) = pk;
      }
    } else {
#pragma unroll
      for (int i = 0; i < 4; ++i)
#pragma unroll
        for (int r = 0; r < 4; ++r) {
          int gm = m0 + wm * 64 + i * 16 + g * 4 + r;
          int b = gm >> 11, s = gm & 2047;
          O[(((size_t)b * 16 + h) * 2048 + s) * 64 + d] =
              f2bf_fast((acc[i][j][r] + bvv) * sc);
        }
    }
  }
}

// grid (32 m-tiles, 8 n-tiles, 3): linear index ≡ m (mod 8) -> XCD keeps a
// fixed quarter of A's rows hot and reuses each W tile 4x in its own L2.
__global__ __launch_bounds__(256) void qkv_gemm_bf16(
    const u16* __restrict__ Xq, const u16* __restrict__ Xk, const u16* __restrict__ Xv,
    const u16* __restrict__ Wq, const u16* __restrict__ Wk, const u16* __restrict__ Wv,
    const void* __restrict__ Bq, const void* __restrict__ Bk, const void* __restrict__ Bv,
    u16* __restrict__ Oq, u16* __restrict__ Ok, u16* __restrict__ Ov)
{
  __align__(16) __shared__ u16 As[8192];
  __align__(16) __shared__ u16 Bs[8192];
  const int z = blockIdx.z;
  const u16* X = (z == 0) ? Xq : (z == 1) ? Xk : Xv;
  const u16* W = (z == 0) ? Wq : (z == 1) ? Wk : Wv;
  const void* Bi = (z == 0) ? Bq : (z == 1) ? Bk : Bv;
  u16* O = (z == 0) ? Oq : (z == 1) ? Ok : Ov;
  const int tid = threadIdx.x;
  const int m0 = blockIdx.x * 128, n0 = blockIdx.y * 128;
  floatx4 acc[4][4] = {};
  gemm_core_bf16(X, W, As, Bs, acc, m0, n0, 1024, tid);
  const int cF32 = probe_is_f32(Bi);   // after core: no stray vmem in loop
  qkv_epilogue(acc, Bi, cF32, O, m0, n0, tid, z);
}

__global__ __launch_bounds__(256) void qkv_gemm_cvt(
    const void* __restrict__ Xq, const void* __restrict__ Xk, const void* __restrict__ Xv,
    const void* __restrict__ Wq, const void* __restrict__ Wk, const void* __restrict__ Wv,
    const void* __restrict__ Bq, const void* __restrict__ Bk, const void* __restrict__ Bv,
    u16* __restrict__ Oq, u16* __restrict__ Ok, u16* __restrict__ Ov)
{
  __align__(16) __shared__ u16 As[4096];
  __align__(16) __shared__ u16 Bs[4096];
  const int z = blockIdx.z;
  const void* X  = (z == 0) ? Xq : (z == 1) ? Xk : Xv;
  const void* W  = (z == 0) ? Wq : (z == 1) ? Wk : Wv;
  const void* Bi = (z == 0) ? Bq : (z == 1) ? Bk : Bv;
  u16* O = (z == 0) ? Oq : (z == 1) ? Ok : Ov;
  const int aF32 = probe_is_f32(X);
  const int bF32 = probe_is_f32(W);
  const int cF32 = probe_is_f32(Bi);
  const int tid = threadIdx.x;
  const int m0 = blockIdx.y * 128, n0 = blockIdx.x * 128;
  floatx4 acc[4][4] = {};
  gemm_core_cvt(X, W, aF32, bF32, As, Bs, acc, m0, n0, 1024, tid);
  qkv_epilogue(acc, Bi, cF32, O, m0, n0, tid, z);
}

// ---------------------------------------------------------------------------
// Output projection: 128x128 tiles, grid (32 m, 8 n) XCD-swizzled, dbuf core.
// fp32 store to d_out.
// ---------------------------------------------------------------------------
__global__ __launch_bounds__(256) void out_gemm_bf16(
    const u16* __restrict__ X, const u16* __restrict__ W,
    const void* __restrict__ Bi, float* __restrict__ O)
{
  __align__(16) __shared__ u16 As[8192];
  __align__(16) __shared__ u16 Bs[8192];
  const int tid = threadIdx.x;
  const int m0 = blockIdx.x * 128, n0 = blockIdx.y * 128;
  floatx4 acc[4][4] = {};
  gemm_core_bf16(X, W, As, Bs, acc, m0, n0, 1024, tid);
  const int cF32 = probe_is_f32(Bi);
  const int lane = tid & 63, wv = tid >> 6;
  const int wm = wv >> 1, wn = wv & 1, g = lane >> 4, ml = lane & 15;
#pragma unroll
  for (int j = 0; j < 4; ++j) {
    int gn = n0 + wn * 64 + j * 16 + ml;
    float bvv = ldscalar(Bi, (size_t)gn, cF32);
#pragma unroll
    for (int i = 0; i < 4; ++i)
#pragma unroll
      for (int r = 0; r < 4; ++r) {
        int gm = m0 + wm * 64 + i * 16 + g * 4 + r;
        O[(size_t)gm * 1024 + gn] = acc[i][j][r] + bvv;
      }
  }
}

__global__ __launch_bounds__(256) void out_gemm_cvt(
    const u16* __restrict__ X, const void* __restrict__ W,
    const void* __restrict__ Bi, float* __restrict__ O)
{
  __align__(16) __shared__ u16 As[4096];
  __align__(16) __shared__ u16 Bs[4096];
  const int bF32 = probe_is_f32(W);
  const int cF32 = probe_is_f32(Bi);
  const int tid = threadIdx.x;
  const int m0 = blockIdx.y * 128, n0 = blockIdx.x * 128;
  floatx4 acc[4][4] = {};
  gemm_core_cvt(X, W, /*aF32=*/0, bF32, As, Bs, acc, m0, n0, 1024, tid);
  const int lane = tid & 63, wv = tid >> 6;
  const int wm = wv >> 1, wn = wv & 1, g = lane >> 4, ml = lane & 15;
#pragma unroll
  for (int j = 0; j < 4; ++j) {
    int gn = n0 + wn * 64 + j * 16 + ml;
    float bvv = ldscalar(Bi, (size_t)gn, cF32);
#pragma unroll
    for (int i = 0; i < 4; ++i)
#pragma unroll
      for (int r = 0; r < 4; ++r) {
        int gm = m0 + wm * 64 + i * 16 + g * 4 + r;
        O[(size_t)gm * 1024 + gn] = acc[i][j][r] + bvv;
      }
  }
}

// ---------------------------------------------------------------------------
// Flash attention v6: K double-buffered + counted-vmcnt pipeline.
// Old structure drained vmcnt(0) at a barrier right after issuing each tile's
// K/V loads -> full L2/HBM latency exposed 32x per block (MfmaUtil 20%,
// VALUBusy 42%, ~38% issue-idle). New per-iter schedule:
//   issue V(kv)->Vt, K(kv+1)->Ks[buf^1]          (4 gll ops)
//   s_waitcnt vmcnt(4); s_barrier                 // K(kv) ready; 4 stay in flight
//   QK^T + softmax + Ps                           // hides V(kv) latency
//   s_waitcnt vmcnt(2); s_barrier                 // V(kv) ready; K-prefetch in flight
//   PV
//   s_barrier                                     // bufs consumable next iter
// vmcnt never drains to 0 inside the loop. LDS 34.1 KB keeps 4 blocks/CU
// (full K+V dbuf would be 42 KB -> 3/CU + a 768/256 tail round: worse).
// s_setprio(1) wraps both MFMA clusters (T5; pays now that waves role-split).
// ---------------------------------------------------------------------------
__global__ __launch_bounds__(256) void flash_attn(
    const u16* __restrict__ Q, const u16* __restrict__ K, const u16* __restrict__ V,
    const int* __restrict__ Mask, u16* __restrict__ O)
{
  __align__(16) __shared__ u16 Ks[2][64 * 64];
  __align__(16) __shared__ u16 Vt[64 * 64];
  __align__(16) __shared__ u16 Ps[4][16 * 72];
  __align__(16) __shared__ int Ms[64];
  __shared__ int Wok[4];

  const int qt = blockIdx.x;
  const int bh = blockIdx.y;
  const int b = bh >> 4, h = bh & 15;
  const int tid = threadIdx.x;
  const int lane = tid & 63, wv = tid >> 6;
  const int g = lane >> 4, ml = lane & 15;

  const size_t baseQ  = (((size_t)b * 16 + h) * 2048 + (size_t)qt * 64) * 64;
  const size_t baseKV = ((size_t)b * 16 + h) * 2048 * 64;  // V is [B,H,D,S]

  {
    int la = 1;
#pragma unroll
    for (int i = 0; i < 8; ++i) la &= Mask[b * 2048 + tid * 8 + i];
    int wall = __all(la != 0);
    if (lane == 0) Wok[wv] = wall;
  }

  short8 qf[2];
#pragma unroll
  for (int ks = 0; ks < 2; ++ks)
    qf[ks] = *(const short8*)(Q + baseQ + (size_t)(wv * 16 + ml) * 64 + ks * 32 + g * 8);

  const u16* kg[2]; const u16* vg[2];
  int lo[2];
#pragma unroll
  for (int t = 0; t < 2; ++t) {
    int s = tid + t * 256;
    int krow = s >> 3, kch = (s & 7) ^ (krow & 7);
    kg[t] = K + baseKV + (size_t)krow * 64 + kch * 8;
    int vd = s >> 3,  vch = (s & 7) ^ (vd & 7);
    vg[t] = V + baseKV + (size_t)vd * 2048 + vch * 8;
    lo[t] = ((tid & 448) + t * 256) * 8;
  }

  // prologue: K tile 0 -> Ks[0] (issued before the Wok barrier; the
  // __syncthreads drain just means iter-0's vmcnt(4) is trivially satisfied)
#pragma unroll
  for (int t = 0; t < 2; ++t)
    __builtin_amdgcn_global_load_lds((const AS_GLOBAL unsigned int*)kg[t],
                                     (AS_LDS unsigned int*)(&Ks[0][0] + lo[t]), 16, 0, 0);

  __syncthreads();
  const bool maskall = Wok[0] && Wok[1] && Wok[2] && Wok[3];

  floatx4 oacc[4] = {};
  float lp[4] = {0.f, 0.f, 0.f, 0.f};

  int buf = 0;
#pragma unroll 2
  for (int kv0 = 0; kv0 < 2048; kv0 += 64) {
    // V(kv0) -> Vt (single-buffered; end-of-prev-iter barrier protects it)
#pragma unroll
    for (int t = 0; t < 2; ++t)
      __builtin_amdgcn_global_load_lds((const AS_GLOBAL unsigned int*)(vg[t] + kv0),
                                       (AS_LDS unsigned int*)(Vt + lo[t]), 16, 0, 0);
    // K(kv0+64) -> Ks[buf^1] (dummy wrap to tile 0 on last iter)
    const int nxt = (kv0 + 64) & 2047;
#pragma unroll
    for (int t = 0; t < 2; ++t)
      __builtin_amdgcn_global_load_lds((const AS_GLOBAL unsigned int*)(kg[t] + (size_t)nxt * 64),
                                       (AS_LDS unsigned int*)(&Ks[buf ^ 1][0] + lo[t]), 16, 0, 0);
    if (!maskall && tid < 64) Ms[tid] = Mask[b * 2048 + kv0 + tid];
    // K(kv0) landed for all waves; 2xV + 2xK-prefetch stay in flight.
    // lgkmcnt(0) makes wave-0's Ms ds_write visible (cold path; ~free hot).
    __asm__ __volatile__("s_waitcnt vmcnt(4) lgkmcnt(0)\n\ts_barrier" ::: "memory");

    const u16* Kc = &Ks[buf][0];
    float sv[4][4];
    __builtin_amdgcn_s_setprio(1);
#pragma unroll
    for (int j = 0; j < 4; ++j) {
      floatx4 a = {0.f, 0.f, 0.f, 0.f};
      int row = j * 16 + ml;
#pragma unroll
      for (int ks = 0; ks < 2; ++ks) {
        short8 kb = *(const short8*)(Kc + row * 64 + ((((ks << 2) + g) ^ (row & 7)) << 3));
        a = __builtin_amdgcn_mfma_f32_16x16x32_bf16(qf[ks], kb, a, 0, 0, 0);
      }
#pragma unroll
      for (int r = 0; r < 4; ++r) sv[j][r] = a[r];
    }
    __builtin_amdgcn_s_setprio(0);
    if (!maskall) {
      int mok[4];
#pragma unroll
      for (int j = 0; j < 4; ++j) mok[j] = Ms[j * 16 + ml];
#pragma unroll
      for (int j = 0; j < 4; ++j)
#pragma unroll
        for (int r = 0; r < 4; ++r)
          sv[j][r] = (mok[j] == 0) ? -1.0e30f : sv[j][r];
    }

#pragma unroll
    for (int j = 0; j < 4; ++j)
#pragma unroll
      for (int r = 0; r < 4; ++r) {
        float p = __builtin_amdgcn_exp2f(sv[j][r]);
        sv[j][r] = p;
        lp[r] += p;
      }

#pragma unroll
    for (int j = 0; j < 4; ++j)
#pragma unroll
      for (int r = 0; r < 4; ++r)
        Ps[wv][(g * 4 + r) * 72 + j * 16 + ml] = f2bf_fast(sv[j][r]);

    // V(kv0) landed for all waves; K-prefetch (2 ops) stays in flight.
    __asm__ __volatile__("s_waitcnt vmcnt(2)\n\ts_barrier" ::: "memory");
    // own Ps writes retired before reading them back
    __asm__ __volatile__("s_waitcnt lgkmcnt(0)" ::: "memory");

    short8 pa[2];
#pragma unroll
    for (int j2 = 0; j2 < 2; ++j2)
      pa[j2] = *(const short8*)(&Ps[wv][ml * 72 + j2 * 32 + g * 8]);
    __builtin_amdgcn_s_setprio(1);
#pragma unroll
    for (int t = 0; t < 4; ++t)
#pragma unroll
      for (int j2 = 0; j2 < 2; ++j2) {
        short8 vb = *(const short8*)(Vt + (t * 16 + ml) * 64 + ((((j2 << 2) + g) ^ (ml & 7)) << 3));
        oacc[t] = __builtin_amdgcn_mfma_f32_16x16x32_bf16(pa[j2], vb, oacc[t], 0, 0, 0);
      }
    __builtin_amdgcn_s_setprio(0);

    // all waves done reading Ks[buf] + Vt -> safe to overwrite next iter
    __asm__ __volatile__("s_barrier" ::: "memory");
    buf ^= 1;
  }
  // drain dummy prefetch before epilogue / endpgm (LDS-dealloc hazard)
  __asm__ __volatile__("s_waitcnt vmcnt(0)" ::: "memory");

  float inv[4];
#pragma unroll
  for (int r = 0; r < 4; ++r) {
    float l = lp[r];
    l += __shfl_xor(l, 1);
    l += __shfl_xor(l, 2);
    l += __shfl_xor(l, 4);
    l += __shfl_xor(l, 8);
    inv[r] = (l > 0.f) ? 1.0f / l : 0.f;
  }
#pragma unroll
  for (int t = 0; t < 4; ++t)
#pragma unroll
    for (int r = 0; r < 4; ++r) {
      int q = qt * 64 + wv * 16 + g * 4 + r;
      int d = t * 16 + ml;
      O[((size_t)b * 2048 + q) * 1024 + h * 64 + d] = f2bf_fast(oacc[t][r] * inv[r]);
    }
}

// ---------------------------------------------------------------------------
extern "C" void kernel_launch(void* const* d_in, const int* in_sizes, int n_in,
                              void* d_out, int out_size, void* d_ws, size_t ws_size,
                              hipStream_t stream) {
  const void* q_in = d_in[0];
  const void* k_in = d_in[1];
  const void* v_in = d_in[2];
  const int* mask = (const int*)d_in[3];
  const void* Wq = d_in[4];  const void* bq = d_in[5];
  const void* Wk = d_in[6];  const void* bk = d_in[7];
  const void* Wv = d_in[8];  const void* bv = d_in[9];
  const void* Wo = d_in[10]; const void* bo = d_in[11];

  const size_t NTOK = (size_t)2 * 2048 * 1024;   // 4,194,304
  const size_t NW   = (size_t)1024 * 1024;       // 1,048,576

  if (ws_size >= (size_t)67108864) {
    u16* CXq = (u16*)d_ws;
    u16* CXk = CXq + NTOK;
    u16* CXv = CXk + NTOK;
    u16* CWq = CXv + NTOK;
    u16* CWk = CWq + NW;
    u16* CWv = CWk + NW;
    u16* CWo = CWv + NW;
    u16* Qp  = CWo + NW;
    u16* Kp  = Qp + NTOK;
    u16* Vp  = Kp + NTOK;   // [B,H,D,S]
    u16* Ao  = Vp + NTOK;

    cvt7<<<dim3(1024, 7), 256, 0, stream>>>(q_in, k_in, v_in, Wq, Wk, Wv, Wo,
                                            CXq, CXk, CXv, CWq, CWk, CWv, CWo);
    qkv_gemm_bf16<<<dim3(32, 8, 3), 256, 0, stream>>>(CXq, CXk, CXv,
                                                      CWq, CWk, CWv,
                                                      bq, bk, bv, Qp, Kp, Vp);
    flash_attn<<<dim3(32, 32), 256, 0, stream>>>(Qp, Kp, Vp, mask, Ao);
    out_gemm_bf16<<<dim3(32, 8), 256, 0, stream>>>(Ao, CWo, bo, (float*)d_out);
  } else {
    u16* Qp = (u16*)d_ws;
    u16* Kp = Qp + NTOK;
    u16* Vp = Kp + NTOK;    // [B,H,D,S]
    u16* Ao = Vp + NTOK;

    qkv_gemm_cvt<<<dim3(8, 32, 3), 256, 0, stream>>>(q_in, k_in, v_in,
                                                     Wq, Wk, Wv, bq, bk, bv,
                                                     Qp, Kp, Vp);
    flash_attn<<<dim3(32, 32), 256, 0, stream>>>(Qp, Kp, Vp, mask, Ao);
    out_gemm_cvt<<<dim3(8, 32), 256, 0, stream>>>(Ao, Wo, bo, (float*)d_out);
  }
}

// Round 2
// 250.033 us; speedup vs baseline: 1.0641x; 1.0641x over previous
//
#include <hip/hip_runtime.h>
#include <stdint.h>

typedef unsigned short u16;
typedef __attribute__((ext_vector_type(8))) short short8;
typedef __attribute__((ext_vector_type(4))) short short4v;
typedef __attribute__((ext_vector_type(4))) float floatx4;
typedef __attribute__((ext_vector_type(2))) unsigned int uint2v;
typedef __attribute__((ext_vector_type(4))) unsigned int uint4v;

#define AS_GLOBAL __attribute__((address_space(1)))
#define AS_LDS    __attribute__((address_space(3)))

// exp2 argument scale folded into Qp: 1/sqrt(1024) * log2(e)
#define QSCALE 0.045084220f

__device__ __forceinline__ float bf2f(u16 u) {
  union { unsigned int i; float f; } x; x.i = ((unsigned int)u) << 16; return x.f;
}
__device__ __forceinline__ u16 f2bf(float f) {          // RNE
  union { float f; unsigned int i; } x; x.f = f;
  unsigned int u = x.i;
  u += 0x7fffu + ((u >> 16) & 1u);
  return (u16)(u >> 16);
}
__device__ __forceinline__ u16 f2bf_fast(float f) {     // round-half-up, 2 ops
  union { float f; unsigned int i; } x; x.f = f;
  return (u16)((x.i + 0x8000u) >> 16);
}

// pack two f32 -> bf16x2 word (v_cvt_pk_bf16_f32: lo -> [15:0], hi -> [31:16])
__device__ __forceinline__ unsigned int cvtpk_bf16(float lo, float hi) {
  unsigned int w;
  __asm__("v_cvt_pk_bf16_f32 %0, %1, %2" : "=v"(w) : "v"(lo), "v"(hi));
  return w;
}

// paired half-swaps (gfx950). After pl32_swap(a,b): a holds the lane<32-half
// words, b the lane>=32-half words (see T12 recipe / flash_attn v7 notes).
__device__ __forceinline__ void pl32_swap(unsigned int& a, unsigned int& b) {
#if __has_builtin(__builtin_amdgcn_permlane32_swap)
  uint2v r = __builtin_amdgcn_permlane32_swap(a, b, false, false);
  a = r[0]; b = r[1];
#else
  __asm__("v_permlane32_swap_b32 %0, %1" : "+v"(a), "+v"(b));
#endif
}
__device__ __forceinline__ void pl16_swap(unsigned int& a, unsigned int& b) {
#if __has_builtin(__builtin_amdgcn_permlane16_swap)
  uint2v r = __builtin_amdgcn_permlane16_swap(a, b, false, false);
  a = r[0]; b = r[1];
#else
  __asm__("v_permlane16_swap_b32 %0, %1" : "+v"(a), "+v"(b));
#endif
}

// Runtime dtype probe (R4-validated).
__device__ __forceinline__ int probe_is_f32(const void* p) {
  const unsigned int* w = (const unsigned int*)p;
  int cnt = 0;
#pragma unroll
  for (int i = 0; i < 64; ++i) {
    unsigned int lo = w[i] & 0xFFFFu;
    int e = (int)((lo >> 7) & 0xFFu);
    cnt += (e >= 117 && e <= 137) ? 1 : 0;
  }
  return cnt < 32;
}

__device__ __forceinline__ short8 ld8(const void* P, size_t off, int isf32) {
  if (isf32) {
    const float* q = (const float*)P + off;
    float4 x = *(const float4*)q;
    float4 y = *(const float4*)(q + 4);
    short8 r;
    r[0] = (short)f2bf(x.x); r[1] = (short)f2bf(x.y);
    r[2] = (short)f2bf(x.z); r[3] = (short)f2bf(x.w);
    r[4] = (short)f2bf(y.x); r[5] = (short)f2bf(y.y);
    r[6] = (short)f2bf(y.z); r[7] = (short)f2bf(y.w);
    return r;
  }
  return *(const short8*)((const u16*)P + off);
}

__device__ __forceinline__ float ldscalar(const void* P, size_t idx, int isf32) {
  return isf32 ? ((const float*)P)[idx] : bf2f(((const u16*)P)[idx]);
}

// ---------------------------------------------------------------------------
// cvt7: one-shot fp32->bf16 of 3 X tensors + 4 W tensors. grid (1024, 7).
// ---------------------------------------------------------------------------
__global__ __launch_bounds__(256) void cvt7(
    const void* s0, const void* s1, const void* s2, const void* s3,
    const void* s4, const void* s5, const void* s6,
    u16* d0, u16* d1, u16* d2, u16* d3, u16* d4, u16* d5, u16* d6)
{
  const int z = blockIdx.y;
  const void* src; u16* dst; int n;
  switch (z) {
    case 0: src = s0; dst = d0; n = 4194304; break;
    case 1: src = s1; dst = d1; n = 4194304; break;
    case 2: src = s2; dst = d2; n = 4194304; break;
    case 3: src = s3; dst = d3; n = 1048576; break;
    case 4: src = s4; dst = d4; n = 1048576; break;
    case 5: src = s5; dst = d5; n = 1048576; break;
    default: src = s6; dst = d6; n = 1048576; break;
  }
  const int isf32 = probe_is_f32(src);
  for (int i = blockIdx.x * 256 + threadIdx.x; i * 4 < n; i += gridDim.x * 256) {
    if (isf32) {
      float4 x = ((const float4*)src)[i];
      short4v r;
      r[0] = (short)f2bf(x.x); r[1] = (short)f2bf(x.y);
      r[2] = (short)f2bf(x.z); r[3] = (short)f2bf(x.w);
      *(short4v*)(dst + (size_t)i * 4) = r;
    } else {
      *(short4v*)(dst + (size_t)i * 4) = ((const short4v*)src)[i];
    }
  }
}

// ---------------------------------------------------------------------------
// bf16 MFMA GEMM core v3: BK=32 + DOUBLE-BUFFERED LDS with raw-asm barriers.
// Prefetch for tile k+1 is issued BEFORE the barrier and stays in flight
// across it (s_waitcnt vmcnt(4), never 0 inside the loop).
// As/Bs must each be 8192 u16 (two 4096 buffers). 128x128 tile, 4 waves.
// ---------------------------------------------------------------------------
__device__ __forceinline__ void gemm_core_bf16(
    const u16* __restrict__ A, const u16* __restrict__ W,
    u16* As, u16* Bs, floatx4 acc[4][4], int m0, int n0, int K, int tid)
{
  const int lane = tid & 63, wv = tid >> 6;
  const int wm = wv >> 1, wn = wv & 1;
  const int g = lane >> 4, ml = lane & 15;
  const int r0 = tid >> 2, kc = (tid & 3) << 3;
  const u16* Ag0 = A + (size_t)(m0 + r0) * K + kc;
  const u16* Ag1 = A + (size_t)(m0 + r0 + 64) * K + kc;
  const u16* Bg0 = W + (size_t)(n0 + r0) * K + kc;
  const u16* Bg1 = W + (size_t)(n0 + r0 + 64) * K + kc;

#define STAGE_QKV(buf_, kt_) do {                                              \
    u16* a0 = As + (buf_) * 4096 + tid * 8;                                    \
    u16* b0 = Bs + (buf_) * 4096 + tid * 8;                                    \
    __builtin_amdgcn_global_load_lds((const AS_GLOBAL unsigned int*)(Ag0 + (kt_)), \
                                     (AS_LDS unsigned int*)a0, 16, 0, 0);      \
    __builtin_amdgcn_global_load_lds((const AS_GLOBAL unsigned int*)(Ag1 + (kt_)), \
                                     (AS_LDS unsigned int*)(a0 + 2048), 16, 0, 0); \
    __builtin_amdgcn_global_load_lds((const AS_GLOBAL unsigned int*)(Bg0 + (kt_)), \
                                     (AS_LDS unsigned int*)b0, 16, 0, 0);      \
    __builtin_amdgcn_global_load_lds((const AS_GLOBAL unsigned int*)(Bg1 + (kt_)), \
                                     (AS_LDS unsigned int*)(b0 + 2048), 16, 0, 0); \
  } while (0)

  STAGE_QKV(0, 0);
  int buf = 0;
#pragma unroll 2
  for (int kt = 0; kt < K; kt += 32) {
    const int nk = (kt + 32 < K) ? (kt + 32) : 0;   // dummy reload on last iter
    STAGE_QKV(buf ^ 1, nk);
    // wait current tile (4 oldest), keep prefetch (4 newest) in flight
    __asm__ __volatile__("s_waitcnt vmcnt(4)\n\ts_barrier" ::: "memory");
    const u16* Ac = As + buf * 4096;
    const u16* Bc = Bs + buf * 4096;
    short8 af[4], bf[4];
#pragma unroll
    for (int i = 0; i < 4; ++i)
      af[i] = *(const short8*)(Ac + (wm * 64 + i * 16 + ml) * 32 + g * 8);
#pragma unroll
    for (int j = 0; j < 4; ++j)
      bf[j] = *(const short8*)(Bc + (wn * 64 + j * 16 + ml) * 32 + g * 8);
#pragma unroll
    for (int i = 0; i < 4; ++i)
#pragma unroll
      for (int j = 0; j < 4; ++j)
        acc[i][j] = __builtin_amdgcn_mfma_f32_16x16x32_bf16(af[i], bf[j], acc[i][j], 0, 0, 0);
    // all waves done reading buf before it becomes next prefetch target
    __asm__ __volatile__("s_waitcnt lgkmcnt(0)\n\ts_barrier" ::: "memory");
    buf ^= 1;
  }
#undef STAGE_QKV
  // drain dummy prefetch before epilogue / endpgm (LDS-dealloc hazard)
  __asm__ __volatile__("s_waitcnt vmcnt(0)" ::: "memory");
}

// R7-proven fallback core: BK=32, cvt-in-staging. (As/Bs = 4096 u16)
__device__ __forceinline__ void gemm_core_cvt(
    const void* __restrict__ A, const void* __restrict__ W, int aF32, int bF32,
    u16* As, u16* Bs, floatx4 acc[4][4], int m0, int n0, int K, int tid)
{
  const int lane = tid & 63, wv = tid >> 6;
  const int wm = wv >> 1, wn = wv & 1;
  const int g = lane >> 4, ml = lane & 15;
  const int r0 = tid >> 2, kc = (tid & 3) << 3;
  const size_t offA0 = (size_t)(m0 + r0) * K + kc;
  const size_t offA1 = (size_t)(m0 + r0 + 64) * K + kc;
  const size_t offB0 = (size_t)(n0 + r0) * K + kc;
  const size_t offB1 = (size_t)(n0 + r0 + 64) * K + kc;
  u16* Al0 = As + tid * 8;  u16* Al1 = As + (tid + 256) * 8;
  u16* Bl0 = Bs + tid * 8;  u16* Bl1 = Bs + (tid + 256) * 8;
  for (int kt = 0; kt < K; kt += 32) {
    short8 a0 = ld8(A, offA0 + kt, aF32);
    short8 a1 = ld8(A, offA1 + kt, aF32);
    short8 b0 = ld8(W, offB0 + kt, bF32);
    short8 b1 = ld8(W, offB1 + kt, bF32);
    *(short8*)Al0 = a0;  *(short8*)Al1 = a1;
    *(short8*)Bl0 = b0;  *(short8*)Bl1 = b1;
    __syncthreads();
    short8 af[4], bf[4];
#pragma unroll
    for (int i = 0; i < 4; ++i)
      af[i] = *(const short8*)(As + (wm * 64 + i * 16 + ml) * 32 + g * 8);
#pragma unroll
    for (int j = 0; j < 4; ++j)
      bf[j] = *(const short8*)(Bs + (wn * 64 + j * 16 + ml) * 32 + g * 8);
#pragma unroll
    for (int i = 0; i < 4; ++i)
#pragma unroll
      for (int j = 0; j < 4; ++j)
        acc[i][j] = __builtin_amdgcn_mfma_f32_16x16x32_bf16(af[i], bf[j], acc[i][j], 0, 0, 0);
    __syncthreads();
  }
}

// ---------------------------------------------------------------------------
// QKV epilogue: z=0 (Q) scaled by QSCALE into [B,H,S,D]; z=1 (K) [B,H,S,D];
// z=2 (V) TRANSPOSED into [B,H,D,S] (4-wide packed along s).
// ---------------------------------------------------------------------------
__device__ __forceinline__ void qkv_epilogue(
    floatx4 acc[4][4], const void* Bi, int cF32, u16* O, int m0, int n0,
    int tid, int z)
{
  const int lane = tid & 63, wv = tid >> 6;
  const int wm = wv >> 1, wn = wv & 1, g = lane >> 4, ml = lane & 15;
  const float sc = (z == 0) ? QSCALE : 1.0f;
#pragma unroll
  for (int j = 0; j < 4; ++j) {
    int gn = n0 + wn * 64 + j * 16 + ml;
    float bvv = ldscalar(Bi, (size_t)gn, cF32);
    int h = gn >> 6, d = gn & 63;
    if (z == 2) {
#pragma unroll
      for (int i = 0; i < 4; ++i) {
        int gm0 = m0 + wm * 64 + i * 16 + g * 4;
        int b = gm0 >> 11, s0 = gm0 & 2047;
        short4v pk;
#pragma unroll
        for (int r = 0; r < 4; ++r) pk[r] = (short)f2bf_fast(acc[i][j][r] + bvv);
        *(short4v*)(O + ((((size_t)b * 16 + h) * 64 + d) * 2048 + s0)) = pk;
      }
    } else {
#pragma unroll
      for (int i = 0; i < 4; ++i)
#pragma unroll
        for (int r = 0; r < 4; ++r) {
          int gm = m0 + wm * 64 + i * 16 + g * 4 + r;
          int b = gm >> 11, s = gm & 2047;
          O[(((size_t)b * 16 + h) * 2048 + s) * 64 + d] =
              f2bf_fast((acc[i][j][r] + bvv) * sc);
        }
    }
  }
}

// grid (32 m-tiles, 8 n-tiles, 3): linear index ≡ m (mod 8) -> XCD keeps a
// fixed quarter of A's rows hot and reuses each W tile 4x in its own L2.
__global__ __launch_bounds__(256) void qkv_gemm_bf16(
    const u16* __restrict__ Xq, const u16* __restrict__ Xk, const u16* __restrict__ Xv,
    const u16* __restrict__ Wq, const u16* __restrict__ Wk, const u16* __restrict__ Wv,
    const void* __restrict__ Bq, const void* __restrict__ Bk, const void* __restrict__ Bv,
    u16* __restrict__ Oq, u16* __restrict__ Ok, u16* __restrict__ Ov)
{
  __align__(16) __shared__ u16 As[8192];
  __align__(16) __shared__ u16 Bs[8192];
  const int z = blockIdx.z;
  const u16* X = (z == 0) ? Xq : (z == 1) ? Xk : Xv;
  const u16* W = (z == 0) ? Wq : (z == 1) ? Wk : Wv;
  const void* Bi = (z == 0) ? Bq : (z == 1) ? Bk : Bv;
  u16* O = (z == 0) ? Oq : (z == 1) ? Ok : Ov;
  const int tid = threadIdx.x;
  const int m0 = blockIdx.x * 128, n0 = blockIdx.y * 128;
  floatx4 acc[4][4] = {};
  gemm_core_bf16(X, W, As, Bs, acc, m0, n0, 1024, tid);
  const int cF32 = probe_is_f32(Bi);   // after core: no stray vmem in loop
  qkv_epilogue(acc, Bi, cF32, O, m0, n0, tid, z);
}

__global__ __launch_bounds__(256) void qkv_gemm_cvt(
    const void* __restrict__ Xq, const void* __restrict__ Xk, const void* __restrict__ Xv,
    const void* __restrict__ Wq, const void* __restrict__ Wk, const void* __restrict__ Wv,
    const void* __restrict__ Bq, const void* __restrict__ Bk, const void* __restrict__ Bv,
    u16* __restrict__ Oq, u16* __restrict__ Ok, u16* __restrict__ Ov)
{
  __align__(16) __shared__ u16 As[4096];
  __align__(16) __shared__ u16 Bs[4096];
  const int z = blockIdx.z;
  const void* X  = (z == 0) ? Xq : (z == 1) ? Xk : Xv;
  const void* W  = (z == 0) ? Wq : (z == 1) ? Wk : Wv;
  const void* Bi = (z == 0) ? Bq : (z == 1) ? Bk : Bv;
  u16* O = (z == 0) ? Oq : (z == 1) ? Ok : Ov;
  const int aF32 = probe_is_f32(X);
  const int bF32 = probe_is_f32(W);
  const int cF32 = probe_is_f32(Bi);
  const int tid = threadIdx.x;
  const int m0 = blockIdx.y * 128, n0 = blockIdx.x * 128;
  floatx4 acc[4][4] = {};
  gemm_core_cvt(X, W, aF32, bF32, As, Bs, acc, m0, n0, 1024, tid);
  qkv_epilogue(acc, Bi, cF32, O, m0, n0, tid, z);
}

// ---------------------------------------------------------------------------
// Output projection: 128x128 tiles, grid (32 m, 8 n) XCD-swizzled, dbuf core.
// fp32 store to d_out.
// ---------------------------------------------------------------------------
__global__ __launch_bounds__(256) void out_gemm_bf16(
    const u16* __restrict__ X, const u16* __restrict__ W,
    const void* __restrict__ Bi, float* __restrict__ O)
{
  __align__(16) __shared__ u16 As[8192];
  __align__(16) __shared__ u16 Bs[8192];
  const int tid = threadIdx.x;
  const int m0 = blockIdx.x * 128, n0 = blockIdx.y * 128;
  floatx4 acc[4][4] = {};
  gemm_core_bf16(X, W, As, Bs, acc, m0, n0, 1024, tid);
  const int cF32 = probe_is_f32(Bi);
  const int lane = tid & 63, wv = tid >> 6;
  const int wm = wv >> 1, wn = wv & 1, g = lane >> 4, ml = lane & 15;
#pragma unroll
  for (int j = 0; j < 4; ++j) {
    int gn = n0 + wn * 64 + j * 16 + ml;
    float bvv = ldscalar(Bi, (size_t)gn, cF32);
#pragma unroll
    for (int i = 0; i < 4; ++i)
#pragma unroll
      for (int r = 0; r < 4; ++r) {
        int gm = m0 + wm * 64 + i * 16 + g * 4 + r;
        O[(size_t)gm * 1024 + gn] = acc[i][j][r] + bvv;
      }
  }
}

__global__ __launch_bounds__(256) void out_gemm_cvt(
    const u16* __restrict__ X, const void* __restrict__ W,
    const void* __restrict__ Bi, float* __restrict__ O)
{
  __align__(16) __shared__ u16 As[4096];
  __align__(16) __shared__ u16 Bs[4096];
  const int bF32 = probe_is_f32(W);
  const int cF32 = probe_is_f32(Bi);
  const int tid = threadIdx.x;
  const int m0 = blockIdx.y * 128, n0 = blockIdx.x * 128;
  floatx4 acc[4][4] = {};
  gemm_core_cvt(X, W, /*aF32=*/0, bF32, As, Bs, acc, m0, n0, 1024, tid);
  const int lane = tid & 63, wv = tid >> 6;
  const int wm = wv >> 1, wn = wv & 1, g = lane >> 4, ml = lane & 15;
#pragma unroll
  for (int j = 0; j < 4; ++j) {
    int gn = n0 + wn * 64 + j * 16 + ml;
    float bvv = ldscalar(Bi, (size_t)gn, cF32);
#pragma unroll
    for (int i = 0; i < 4; ++i)
#pragma unroll
      for (int r = 0; r < 4; ++r) {
        int gm = m0 + wm * 64 + i * 16 + g * 4 + r;
        O[(size_t)gm * 1024 + gn] = acc[i][j][r] + bvv;
      }
  }
}

// ---------------------------------------------------------------------------
// Flash attention v7: K-dbuf counted-vmcnt pipeline (from v6) + swapped-QK^T
// in-register softmax (T12) that DELETES the Ps LDS buffer.
// R1 post-mortem: v6's 33.5 KB LDS cut residency 6->4 blocks/CU and occupancy
// fell 35->23% (TLP was the real latency-hider). v7 keeps the pipeline but
// drops LDS to ~24.9 KB -> 6 blocks/CU again.
//
// Swapped QK^T: sv[j][r] = mfma(K_j, Q) = P[k=j*16+g*4+r][q=ml] -- each lane
// holds 16 P values all for its own q-row (q=ml). P -> PV-A-frag is then a
// pure in-register transpose over the 4 g-groups:
//   W[j][w]   = cvt_pk_bf16(P[r=2w], P[r=2w+1])            (8 words)
//   (ua,ub)   = permlane32_swap(W[2jd][w], W[2jd+1][w])    -> j&1 = g1 routed
//   (ua,ub)   = permlane16_swap(ua, ub)                    -> g'1 = g0 routed
//   pa[ks]    = { Zl[ks][0], Zl[ks][1], Zh[ks][0], Zh[ks][1] }
// (routing verified elementwise: word p of pa[ks] = P[q=ml][k=ks*32+g*8+2p{,+1}])
// Removes 16 ds_write_u16 + 2 ds_read_b128 + lgkmcnt stall + 9.2 KB LDS/tile.
// Row-sum: one scalar lp per lane (q=ml); cross-g reduce hoisted out of loop.
// ---------------------------------------------------------------------------
__global__ __launch_bounds__(256) void flash_attn(
    const u16* __restrict__ Q, const u16* __restrict__ K, const u16* __restrict__ V,
    const int* __restrict__ Mask, u16* __restrict__ O)
{
  __align__(16) __shared__ u16 Ks[2][64 * 64];
  __align__(16) __shared__ u16 Vt[64 * 64];
  __align__(16) __shared__ int Ms[64];
  __shared__ int Wok[4];

  const int qt = blockIdx.x;
  const int bh = blockIdx.y;
  const int b = bh >> 4, h = bh & 15;
  const int tid = threadIdx.x;
  const int lane = tid & 63, wv = tid >> 6;
  const int g = lane >> 4, ml = lane & 15;

  const size_t baseQ  = (((size_t)b * 16 + h) * 2048 + (size_t)qt * 64) * 64;
  const size_t baseKV = ((size_t)b * 16 + h) * 2048 * 64;  // V is [B,H,D,S]

  {
    int la = 1;
#pragma unroll
    for (int i = 0; i < 8; ++i) la &= Mask[b * 2048 + tid * 8 + i];
    int wall = __all(la != 0);
    if (lane == 0) Wok[wv] = wall;
  }

  short8 qf[2];
#pragma unroll
  for (int ks = 0; ks < 2; ++ks)
    qf[ks] = *(const short8*)(Q + baseQ + (size_t)(wv * 16 + ml) * 64 + ks * 32 + g * 8);

  const u16* kg[2]; const u16* vg[2];
  int lo[2];
#pragma unroll
  for (int t = 0; t < 2; ++t) {
    int s = tid + t * 256;
    int krow = s >> 3, kch = (s & 7) ^ (krow & 7);
    kg[t] = K + baseKV + (size_t)krow * 64 + kch * 8;
    int vd = s >> 3,  vch = (s & 7) ^ (vd & 7);
    vg[t] = V + baseKV + (size_t)vd * 2048 + vch * 8;
    lo[t] = ((tid & 448) + t * 256) * 8;
  }

  // prologue: K tile 0 -> Ks[0]
#pragma unroll
  for (int t = 0; t < 2; ++t)
    __builtin_amdgcn_global_load_lds((const AS_GLOBAL unsigned int*)kg[t],
                                     (AS_LDS unsigned int*)(&Ks[0][0] + lo[t]), 16, 0, 0);

  __syncthreads();
  const bool maskall = Wok[0] && Wok[1] && Wok[2] && Wok[3];

  floatx4 oacc[4] = {};
  float lp = 0.f;

  int buf = 0;
#pragma unroll 2
  for (int kv0 = 0; kv0 < 2048; kv0 += 64) {
    // V(kv0) -> Vt (single-buffered; end-of-prev-iter barrier protects it)
#pragma unroll
    for (int t = 0; t < 2; ++t)
      __builtin_amdgcn_global_load_lds((const AS_GLOBAL unsigned int*)(vg[t] + kv0),
                                       (AS_LDS unsigned int*)(Vt + lo[t]), 16, 0, 0);
    // K(kv0+64) -> Ks[buf^1] (dummy wrap to tile 0 on last iter)
    const int nxt = (kv0 + 64) & 2047;
#pragma unroll
    for (int t = 0; t < 2; ++t)
      __builtin_amdgcn_global_load_lds((const AS_GLOBAL unsigned int*)(kg[t] + (size_t)nxt * 64),
                                       (AS_LDS unsigned int*)(&Ks[buf ^ 1][0] + lo[t]), 16, 0, 0);
    if (!maskall && tid < 64) Ms[tid] = Mask[b * 2048 + kv0 + tid];
    // K(kv0) landed for all waves; 2xV + 2xK-prefetch stay in flight.
    __asm__ __volatile__("s_waitcnt vmcnt(4) lgkmcnt(0)\n\ts_barrier" ::: "memory");

    const u16* Kc = &Ks[buf][0];
    float sv[4][4];
    __builtin_amdgcn_s_setprio(1);
#pragma unroll
    for (int j = 0; j < 4; ++j) {
      floatx4 a = {0.f, 0.f, 0.f, 0.f};
      int row = j * 16 + ml;
#pragma unroll
      for (int ks = 0; ks < 2; ++ks) {
        short8 kb = *(const short8*)(Kc + row * 64 + ((((ks << 2) + g) ^ (row & 7)) << 3));
        // SWAPPED: A = K rows, B = Q rows  ->  sv[j][r] = P[k=j*16+g*4+r][q=ml]
        a = __builtin_amdgcn_mfma_f32_16x16x32_bf16(kb, qf[ks], a, 0, 0, 0);
      }
#pragma unroll
      for (int r = 0; r < 4; ++r) sv[j][r] = a[r];
    }
    __builtin_amdgcn_s_setprio(0);
    if (!maskall) {
#pragma unroll
      for (int j = 0; j < 4; ++j)
#pragma unroll
        for (int r = 0; r < 4; ++r)
          if (Ms[j * 16 + g * 4 + r] == 0) sv[j][r] = -1.0e30f;
    }

#pragma unroll
    for (int j = 0; j < 4; ++j)
#pragma unroll
      for (int r = 0; r < 4; ++r) {
        float p = __builtin_amdgcn_exp2f(sv[j][r]);
        sv[j][r] = p;
        lp += p;
      }

    // ---- in-register P transpose (no LDS) ----
    unsigned int Wd[4][2];
#pragma unroll
    for (int j = 0; j < 4; ++j)
#pragma unroll
      for (int w = 0; w < 2; ++w)
        Wd[j][w] = cvtpk_bf16(sv[j][2 * w], sv[j][2 * w + 1]);

    unsigned int Zl[2][2], Zh[2][2];
#pragma unroll
    for (int jd = 0; jd < 2; ++jd)
#pragma unroll
      for (int w = 0; w < 2; ++w) {
        unsigned int ua = Wd[2 * jd][w];       // even-j word
        unsigned int ub = Wd[2 * jd + 1][w];   // odd-j word
        pl32_swap(ua, ub);                     // route j&1 -> own g1
        pl16_swap(ua, ub);                     // route g'1 -> own g0
        Zl[jd][w] = ua;                        // g'0 = 0 half
        Zh[jd][w] = ub;                        // g'0 = 1 half
      }

    short8 pa[2];
#pragma unroll
    for (int ks = 0; ks < 2; ++ks) {
      uint4v pw;
      pw[0] = Zl[ks][0]; pw[1] = Zl[ks][1];
      pw[2] = Zh[ks][0]; pw[3] = Zh[ks][1];
      pa[ks] = __builtin_bit_cast(short8, pw);
    }

    // V(kv0) landed for all waves; K-prefetch (2 ops) stays in flight.
    __asm__ __volatile__("s_waitcnt vmcnt(2)\n\ts_barrier" ::: "memory");

    __builtin_amdgcn_s_setprio(1);
#pragma unroll
    for (int t = 0; t < 4; ++t)
#pragma unroll
      for (int j2 = 0; j2 < 2; ++j2) {
        short8 vb = *(const short8*)(Vt + (t * 16 + ml) * 64 + ((((j2 << 2) + g) ^ (ml & 7)) << 3));
        oacc[t] = __builtin_amdgcn_mfma_f32_16x16x32_bf16(pa[j2], vb, oacc[t], 0, 0, 0);
      }
    __builtin_amdgcn_s_setprio(0);

    // all waves done reading Ks[buf] + Vt -> safe to overwrite next iter
    __asm__ __volatile__("s_barrier" ::: "memory");
    buf ^= 1;
  }
  // drain dummy prefetch before epilogue / endpgm (LDS-dealloc hazard)
  __asm__ __volatile__("s_waitcnt vmcnt(0)" ::: "memory");

  // full row-sum for q=ml: reduce the 4 g-partials
  float l = lp;
  l += __shfl_xor(l, 16);
  l += __shfl_xor(l, 32);
  // redistribute: this lane's oacc rows are q = g*4+r -> fetch l from lane
  // with ml = g*4+r (same g group; value is g-replicated anyway)
  float inv[4];
#pragma unroll
  for (int r = 0; r < 4; ++r) {
    float lr = __shfl(l, (lane & 48) | (((lane >> 4) & 3) * 4 + r));
    inv[r] = (lr > 0.f) ? 1.0f / lr : 0.f;
  }
#pragma unroll
  for (int t = 0; t < 4; ++t)
#pragma unroll
    for (int r = 0; r < 4; ++r) {
      int q = qt * 64 + wv * 16 + g * 4 + r;
      int d = t * 16 + ml;
      O[((size_t)b * 2048 + q) * 1024 + h * 64 + d] = f2bf_fast(oacc[t][r] * inv[r]);
    }
}

// ---------------------------------------------------------------------------
extern "C" void kernel_launch(void* const* d_in, const int* in_sizes, int n_in,
                              void* d_out, int out_size, void* d_ws, size_t ws_size,
                              hipStream_t stream) {
  const void* q_in = d_in[0];
  const void* k_in = d_in[1];
  const void* v_in = d_in[2];
  const int* mask = (const int*)d_in[3];
  const void* Wq = d_in[4];  const void* bq = d_in[5];
  const void* Wk = d_in[6];  const void* bk = d_in[7];
  const void* Wv = d_in[8];  const void* bv = d_in[9];
  const void* Wo = d_in[10]; const void* bo = d_in[11];

  const size_t NTOK = (size_t)2 * 2048 * 1024;   // 4,194,304
  const size_t NW   = (size_t)1024 * 1024;       // 1,048,576

  if (ws_size >= (size_t)67108864) {
    u16* CXq = (u16*)d_ws;
    u16* CXk = CXq + NTOK;
    u16* CXv = CXk + NTOK;
    u16* CWq = CXv + NTOK;
    u16* CWk = CWq + NW;
    u16* CWv = CWk + NW;
    u16* CWo = CWv + NW;
    u16* Qp  = CWo + NW;
    u16* Kp  = Qp + NTOK;
    u16* Vp  = Kp + NTOK;   // [B,H,D,S]
    u16* Ao  = Vp + NTOK;

    cvt7<<<dim3(1024, 7), 256, 0, stream>>>(q_in, k_in, v_in, Wq, Wk, Wv, Wo,
                                            CXq, CXk, CXv, CWq, CWk, CWv, CWo);
    qkv_gemm_bf16<<<dim3(32, 8, 3), 256, 0, stream>>>(CXq, CXk, CXv,
                                                      CWq, CWk, CWv,
                                                      bq, bk, bv, Qp, Kp, Vp);
    flash_attn<<<dim3(32, 32), 256, 0, stream>>>(Qp, Kp, Vp, mask, Ao);
    out_gemm_bf16<<<dim3(32, 8), 256, 0, stream>>>(Ao, CWo, bo, (float*)d_out);
  } else {
    u16* Qp = (u16*)d_ws;
    u16* Kp = Qp + NTOK;
    u16* Vp = Kp + NTOK;    // [B,H,D,S]
    u16* Ao = Vp + NTOK;

    qkv_gemm_cvt<<<dim3(8, 32, 3), 256, 0, stream>>>(q_in, k_in, v_in,
                                                     Wq, Wk, Wv, bq, bk, bv,
                                                     Qp, Kp, Vp);
    flash_attn<<<dim3(32, 32), 256, 0, stream>>>(Qp, Kp, Vp, mask, Ao);
    out_gemm_cvt<<<dim3(8, 32), 256, 0, stream>>>(Ao, Wo, bo, (float*)d_out);
  }
}

// Round 3
// 248.027 us; speedup vs baseline: 1.0727x; 1.0081x over previous
//
#include <hip/hip_runtime.h>
#include <stdint.h>

typedef unsigned short u16;
typedef __attribute__((ext_vector_type(8))) short short8;
typedef __attribute__((ext_vector_type(4))) short short4v;
typedef __attribute__((ext_vector_type(4))) float floatx4;
typedef __attribute__((ext_vector_type(16))) float floatx16;
typedef __attribute__((ext_vector_type(2))) unsigned int uint2v;
typedef __attribute__((ext_vector_type(4))) unsigned int uint4v;

#define AS_GLOBAL __attribute__((address_space(1)))
#define AS_LDS    __attribute__((address_space(3)))

// exp2 argument scale folded into Qp: 1/sqrt(1024) * log2(e)
#define QSCALE 0.045084220f

__device__ __forceinline__ float bf2f(u16 u) {
  union { unsigned int i; float f; } x; x.i = ((unsigned int)u) << 16; return x.f;
}
__device__ __forceinline__ u16 f2bf(float f) {          // RNE
  union { float f; unsigned int i; } x; x.f = f;
  unsigned int u = x.i;
  u += 0x7fffu + ((u >> 16) & 1u);
  return (u16)(u >> 16);
}
__device__ __forceinline__ u16 f2bf_fast(float f) {     // round-half-up, 2 ops
  union { float f; unsigned int i; } x; x.f = f;
  return (u16)((x.i + 0x8000u) >> 16);
}

// pack two f32 -> bf16x2 word (v_cvt_pk_bf16_f32: lo -> [15:0], hi -> [31:16])
__device__ __forceinline__ unsigned int cvtpk_bf16(float lo, float hi) {
  unsigned int w;
  __asm__("v_cvt_pk_bf16_f32 %0, %1, %2" : "=v"(w) : "v"(lo), "v"(hi));
  return w;
}

// paired half-swap (gfx950): a' = {a.lo, b.lo}, b' = {a.hi, b.hi}
__device__ __forceinline__ void pl32_swap(unsigned int& a, unsigned int& b) {
#if __has_builtin(__builtin_amdgcn_permlane32_swap)
  uint2v r = __builtin_amdgcn_permlane32_swap(a, b, false, false);
  a = r[0]; b = r[1];
#else
  __asm__("v_permlane32_swap_b32 %0, %1" : "+v"(a), "+v"(b));
#endif
}

// Runtime dtype probe (R4-validated).
__device__ __forceinline__ int probe_is_f32(const void* p) {
  const unsigned int* w = (const unsigned int*)p;
  int cnt = 0;
#pragma unroll
  for (int i = 0; i < 64; ++i) {
    unsigned int lo = w[i] & 0xFFFFu;
    int e = (int)((lo >> 7) & 0xFFu);
    cnt += (e >= 117 && e <= 137) ? 1 : 0;
  }
  return cnt < 32;
}

__device__ __forceinline__ short8 ld8(const void* P, size_t off, int isf32) {
  if (isf32) {
    const float* q = (const float*)P + off;
    float4 x = *(const float4*)q;
    float4 y = *(const float4*)(q + 4);
    short8 r;
    r[0] = (short)f2bf(x.x); r[1] = (short)f2bf(x.y);
    r[2] = (short)f2bf(x.z); r[3] = (short)f2bf(x.w);
    r[4] = (short)f2bf(y.x); r[5] = (short)f2bf(y.y);
    r[6] = (short)f2bf(y.z); r[7] = (short)f2bf(y.w);
    return r;
  }
  return *(const short8*)((const u16*)P + off);
}

__device__ __forceinline__ float ldscalar(const void* P, size_t idx, int isf32) {
  return isf32 ? ((const float*)P)[idx] : bf2f(((const u16*)P)[idx]);
}

// ---------------------------------------------------------------------------
// cvt7: one-shot fp32->bf16 of 3 X tensors + 4 W tensors. grid (1024, 7).
// ---------------------------------------------------------------------------
__global__ __launch_bounds__(256) void cvt7(
    const void* s0, const void* s1, const void* s2, const void* s3,
    const void* s4, const void* s5, const void* s6,
    u16* d0, u16* d1, u16* d2, u16* d3, u16* d4, u16* d5, u16* d6)
{
  const int z = blockIdx.y;
  const void* src; u16* dst; int n;
  switch (z) {
    case 0: src = s0; dst = d0; n = 4194304; break;
    case 1: src = s1; dst = d1; n = 4194304; break;
    case 2: src = s2; dst = d2; n = 4194304; break;
    case 3: src = s3; dst = d3; n = 1048576; break;
    case 4: src = s4; dst = d4; n = 1048576; break;
    case 5: src = s5; dst = d5; n = 1048576; break;
    default: src = s6; dst = d6; n = 1048576; break;
  }
  const int isf32 = probe_is_f32(src);
  for (int i = blockIdx.x * 256 + threadIdx.x; i * 4 < n; i += gridDim.x * 256) {
    if (isf32) {
      float4 x = ((const float4*)src)[i];
      short4v r;
      r[0] = (short)f2bf(x.x); r[1] = (short)f2bf(x.y);
      r[2] = (short)f2bf(x.z); r[3] = (short)f2bf(x.w);
      *(short4v*)(dst + (size_t)i * 4) = r;
    } else {
      *(short4v*)(dst + (size_t)i * 4) = ((const short4v*)src)[i];
    }
  }
}

// ---------------------------------------------------------------------------
// bf16 MFMA GEMM core v3: BK=32 + DOUBLE-BUFFERED LDS with raw-asm barriers.
// Prefetch for tile k+1 is issued BEFORE the barrier and stays in flight
// across it (s_waitcnt vmcnt(4), never 0 inside the loop).
// As/Bs must each be 8192 u16 (two 4096 buffers). 128x128 tile, 4 waves.
// ---------------------------------------------------------------------------
__device__ __forceinline__ void gemm_core_bf16(
    const u16* __restrict__ A, const u16* __restrict__ W,
    u16* As, u16* Bs, floatx4 acc[4][4], int m0, int n0, int K, int tid)
{
  const int lane = tid & 63, wv = tid >> 6;
  const int wm = wv >> 1, wn = wv & 1;
  const int g = lane >> 4, ml = lane & 15;
  const int r0 = tid >> 2, kc = (tid & 3) << 3;
  const u16* Ag0 = A + (size_t)(m0 + r0) * K + kc;
  const u16* Ag1 = A + (size_t)(m0 + r0 + 64) * K + kc;
  const u16* Bg0 = W + (size_t)(n0 + r0) * K + kc;
  const u16* Bg1 = W + (size_t)(n0 + r0 + 64) * K + kc;

#define STAGE_QKV(buf_, kt_) do {                                              \
    u16* a0 = As + (buf_) * 4096 + tid * 8;                                    \
    u16* b0 = Bs + (buf_) * 4096 + tid * 8;                                    \
    __builtin_amdgcn_global_load_lds((const AS_GLOBAL unsigned int*)(Ag0 + (kt_)), \
                                     (AS_LDS unsigned int*)a0, 16, 0, 0);      \
    __builtin_amdgcn_global_load_lds((const AS_GLOBAL unsigned int*)(Ag1 + (kt_)), \
                                     (AS_LDS unsigned int*)(a0 + 2048), 16, 0, 0); \
    __builtin_amdgcn_global_load_lds((const AS_GLOBAL unsigned int*)(Bg0 + (kt_)), \
                                     (AS_LDS unsigned int*)b0, 16, 0, 0);      \
    __builtin_amdgcn_global_load_lds((const AS_GLOBAL unsigned int*)(Bg1 + (kt_)), \
                                     (AS_LDS unsigned int*)(b0 + 2048), 16, 0, 0); \
  } while (0)

  STAGE_QKV(0, 0);
  int buf = 0;
#pragma unroll 2
  for (int kt = 0; kt < K; kt += 32) {
    const int nk = (kt + 32 < K) ? (kt + 32) : 0;   // dummy reload on last iter
    STAGE_QKV(buf ^ 1, nk);
    // wait current tile (4 oldest), keep prefetch (4 newest) in flight
    __asm__ __volatile__("s_waitcnt vmcnt(4)\n\ts_barrier" ::: "memory");
    const u16* Ac = As + buf * 4096;
    const u16* Bc = Bs + buf * 4096;
    short8 af[4], bf[4];
#pragma unroll
    for (int i = 0; i < 4; ++i)
      af[i] = *(const short8*)(Ac + (wm * 64 + i * 16 + ml) * 32 + g * 8);
#pragma unroll
    for (int j = 0; j < 4; ++j)
      bf[j] = *(const short8*)(Bc + (wn * 64 + j * 16 + ml) * 32 + g * 8);
#pragma unroll
    for (int i = 0; i < 4; ++i)
#pragma unroll
      for (int j = 0; j < 4; ++j)
        acc[i][j] = __builtin_amdgcn_mfma_f32_16x16x32_bf16(af[i], bf[j], acc[i][j], 0, 0, 0);
    // all waves done reading buf before it becomes next prefetch target
    __asm__ __volatile__("s_waitcnt lgkmcnt(0)\n\ts_barrier" ::: "memory");
    buf ^= 1;
  }
#undef STAGE_QKV
  // drain dummy prefetch before epilogue / endpgm (LDS-dealloc hazard)
  __asm__ __volatile__("s_waitcnt vmcnt(0)" ::: "memory");
}

// R7-proven fallback core: BK=32, cvt-in-staging. (As/Bs = 4096 u16)
__device__ __forceinline__ void gemm_core_cvt(
    const void* __restrict__ A, const void* __restrict__ W, int aF32, int bF32,
    u16* As, u16* Bs, floatx4 acc[4][4], int m0, int n0, int K, int tid)
{
  const int lane = tid & 63, wv = tid >> 6;
  const int wm = wv >> 1, wn = wv & 1;
  const int g = lane >> 4, ml = lane & 15;
  const int r0 = tid >> 2, kc = (tid & 3) << 3;
  const size_t offA0 = (size_t)(m0 + r0) * K + kc;
  const size_t offA1 = (size_t)(m0 + r0 + 64) * K + kc;
  const size_t offB0 = (size_t)(n0 + r0) * K + kc;
  const size_t offB1 = (size_t)(n0 + r0 + 64) * K + kc;
  u16* Al0 = As + tid * 8;  u16* Al1 = As + (tid + 256) * 8;
  u16* Bl0 = Bs + tid * 8;  u16* Bl1 = Bs + (tid + 256) * 8;
  for (int kt = 0; kt < K; kt += 32) {
    short8 a0 = ld8(A, offA0 + kt, aF32);
    short8 a1 = ld8(A, offA1 + kt, aF32);
    short8 b0 = ld8(W, offB0 + kt, bF32);
    short8 b1 = ld8(W, offB1 + kt, bF32);
    *(short8*)Al0 = a0;  *(short8*)Al1 = a1;
    *(short8*)Bl0 = b0;  *(short8*)Bl1 = b1;
    __syncthreads();
    short8 af[4], bf[4];
#pragma unroll
    for (int i = 0; i < 4; ++i)
      af[i] = *(const short8*)(As + (wm * 64 + i * 16 + ml) * 32 + g * 8);
#pragma unroll
    for (int j = 0; j < 4; ++j)
      bf[j] = *(const short8*)(Bs + (wn * 64 + j * 16 + ml) * 32 + g * 8);
#pragma unroll
    for (int i = 0; i < 4; ++i)
#pragma unroll
      for (int j = 0; j < 4; ++j)
        acc[i][j] = __builtin_amdgcn_mfma_f32_16x16x32_bf16(af[i], bf[j], acc[i][j], 0, 0, 0);
    __syncthreads();
  }
}

// ---------------------------------------------------------------------------
// QKV epilogue: z=0 (Q) scaled by QSCALE into [B,H,S,D]; z=1 (K) [B,H,S,D];
// z=2 (V) TRANSPOSED into [B,H,D,S] (4-wide packed along s).
// ---------------------------------------------------------------------------
__device__ __forceinline__ void qkv_epilogue(
    floatx4 acc[4][4], const void* Bi, int cF32, u16* O, int m0, int n0,
    int tid, int z)
{
  const int lane = tid & 63, wv = tid >> 6;
  const int wm = wv >> 1, wn = wv & 1, g = lane >> 4, ml = lane & 15;
  const float sc = (z == 0) ? QSCALE : 1.0f;
#pragma unroll
  for (int j = 0; j < 4; ++j) {
    int gn = n0 + wn * 64 + j * 16 + ml;
    float bvv = ldscalar(Bi, (size_t)gn, cF32);
    int h = gn >> 6, d = gn & 63;
    if (z == 2) {
#pragma unroll
      for (int i = 0; i < 4; ++i) {
        int gm0 = m0 + wm * 64 + i * 16 + g * 4;
        int b = gm0 >> 11, s0 = gm0 & 2047;
        short4v pk;
#pragma unroll
        for (int r = 0; r < 4; ++r) pk[r] = (short)f2bf_fast(acc[i][j][r] + bvv);
        *(short4v*)(O + ((((size_t)b * 16 + h) * 64 + d) * 2048 + s0)) = pk;
      }
    } else {
#pragma unroll
      for (int i = 0; i < 4; ++i)
#pragma unroll
        for (int r = 0; r < 4; ++r) {
          int gm = m0 + wm * 64 + i * 16 + g * 4 + r;
          int b = gm >> 11, s = gm & 2047;
          O[(((size_t)b * 16 + h) * 2048 + s) * 64 + d] =
              f2bf_fast((acc[i][j][r] + bvv) * sc);
        }
    }
  }
}

// grid (32 m-tiles, 8 n-tiles, 3): linear index ≡ m (mod 8) -> XCD keeps a
// fixed quarter of A's rows hot and reuses each W tile 4x in its own L2.
__global__ __launch_bounds__(256) void qkv_gemm_bf16(
    const u16* __restrict__ Xq, const u16* __restrict__ Xk, const u16* __restrict__ Xv,
    const u16* __restrict__ Wq, const u16* __restrict__ Wk, const u16* __restrict__ Wv,
    const void* __restrict__ Bq, const void* __restrict__ Bk, const void* __restrict__ Bv,
    u16* __restrict__ Oq, u16* __restrict__ Ok, u16* __restrict__ Ov)
{
  __align__(16) __shared__ u16 As[8192];
  __align__(16) __shared__ u16 Bs[8192];
  const int z = blockIdx.z;
  const u16* X = (z == 0) ? Xq : (z == 1) ? Xk : Xv;
  const u16* W = (z == 0) ? Wq : (z == 1) ? Wk : Wv;
  const void* Bi = (z == 0) ? Bq : (z == 1) ? Bk : Bv;
  u16* O = (z == 0) ? Oq : (z == 1) ? Ok : Ov;
  const int tid = threadIdx.x;
  const int m0 = blockIdx.x * 128, n0 = blockIdx.y * 128;
  floatx4 acc[4][4] = {};
  gemm_core_bf16(X, W, As, Bs, acc, m0, n0, 1024, tid);
  const int cF32 = probe_is_f32(Bi);   // after core: no stray vmem in loop
  qkv_epilogue(acc, Bi, cF32, O, m0, n0, tid, z);
}

__global__ __launch_bounds__(256) void qkv_gemm_cvt(
    const void* __restrict__ Xq, const void* __restrict__ Xk, const void* __restrict__ Xv,
    const void* __restrict__ Wq, const void* __restrict__ Wk, const void* __restrict__ Wv,
    const void* __restrict__ Bq, const void* __restrict__ Bk, const void* __restrict__ Bv,
    u16* __restrict__ Oq, u16* __restrict__ Ok, u16* __restrict__ Ov)
{
  __align__(16) __shared__ u16 As[4096];
  __align__(16) __shared__ u16 Bs[4096];
  const int z = blockIdx.z;
  const void* X  = (z == 0) ? Xq : (z == 1) ? Xk : Xv;
  const void* W  = (z == 0) ? Wq : (z == 1) ? Wk : Wv;
  const void* Bi = (z == 0) ? Bq : (z == 1) ? Bk : Bv;
  u16* O = (z == 0) ? Oq : (z == 1) ? Ok : Ov;
  const int aF32 = probe_is_f32(X);
  const int bF32 = probe_is_f32(W);
  const int cF32 = probe_is_f32(Bi);
  const int tid = threadIdx.x;
  const int m0 = blockIdx.y * 128, n0 = blockIdx.x * 128;
  floatx4 acc[4][4] = {};
  gemm_core_cvt(X, W, aF32, bF32, As, Bs, acc, m0, n0, 1024, tid);
  qkv_epilogue(acc, Bi, cF32, O, m0, n0, tid, z);
}

// ---------------------------------------------------------------------------
// Output projection: 128x128 tiles, grid (32 m, 8 n) XCD-swizzled, dbuf core.
// fp32 store to d_out.
// ---------------------------------------------------------------------------
__global__ __launch_bounds__(256) void out_gemm_bf16(
    const u16* __restrict__ X, const u16* __restrict__ W,
    const void* __restrict__ Bi, float* __restrict__ O)
{
  __align__(16) __shared__ u16 As[8192];
  __align__(16) __shared__ u16 Bs[8192];
  const int tid = threadIdx.x;
  const int m0 = blockIdx.x * 128, n0 = blockIdx.y * 128;
  floatx4 acc[4][4] = {};
  gemm_core_bf16(X, W, As, Bs, acc, m0, n0, 1024, tid);
  const int cF32 = probe_is_f32(Bi);
  const int lane = tid & 63, wv = tid >> 6;
  const int wm = wv >> 1, wn = wv & 1, g = lane >> 4, ml = lane & 15;
#pragma unroll
  for (int j = 0; j < 4; ++j) {
    int gn = n0 + wn * 64 + j * 16 + ml;
    float bvv = ldscalar(Bi, (size_t)gn, cF32);
#pragma unroll
    for (int i = 0; i < 4; ++i)
#pragma unroll
      for (int r = 0; r < 4; ++r) {
        int gm = m0 + wm * 64 + i * 16 + g * 4 + r;
        O[(size_t)gm * 1024 + gn] = acc[i][j][r] + bvv;
      }
  }
}

__global__ __launch_bounds__(256) void out_gemm_cvt(
    const u16* __restrict__ X, const void* __restrict__ W,
    const void* __restrict__ Bi, float* __restrict__ O)
{
  __align__(16) __shared__ u16 As[4096];
  __align__(16) __shared__ u16 Bs[4096];
  const int bF32 = probe_is_f32(W);
  const int cF32 = probe_is_f32(Bi);
  const int tid = threadIdx.x;
  const int m0 = blockIdx.y * 128, n0 = blockIdx.x * 128;
  floatx4 acc[4][4] = {};
  gemm_core_cvt(X, W, /*aF32=*/0, bF32, As, Bs, acc, m0, n0, 1024, tid);
  const int lane = tid & 63, wv = tid >> 6;
  const int wm = wv >> 1, wn = wv & 1, g = lane >> 4, ml = lane & 15;
#pragma unroll
  for (int j = 0; j < 4; ++j) {
    int gn = n0 + wn * 64 + j * 16 + ml;
    float bvv = ldscalar(Bi, (size_t)gn, cF32);
#pragma unroll
    for (int i = 0; i < 4; ++i)
#pragma unroll
      for (int r = 0; r < 4; ++r) {
        int gm = m0 + wm * 64 + i * 16 + g * 4 + r;
        O[(size_t)gm * 1024 + gn] = acc[i][j][r] + bvv;
      }
  }
}

// ---------------------------------------------------------------------------
// Flash attention v8: 32x32x16 MFMA restructure. R2 analysis: each wave read
// full K+V tiles (16 KB/iter) serving only 16 q-rows -> LDS read BW (~8.4
// MB/CU @ ~100B/cyc ~= 35us) was ~60% of the 57us wall. v8: 2 waves x 32
// q-rows (128 thr), same grid (32,32), same K-dbuf counted-vmcnt pipeline;
// LDS reads per unit work halve; MFMA cycle efficiency +20% (32x32 rate).
//
// Swapped QK^T at 32x32: a_h = mfma(K_h, Q) -> a_h[r] = P[kv = 32h + (r&3)
// + 8*(r>>2) + 4H][q = lq]  (H = lane>>5, lq = lane&31). Each lane holds a
// full q-column. P -> PV A-frag (A[q][kv]) per 16-kv chunk c:
//   W[h][i] = cvt_pk(P_h[2i], P_h[2i+1])            (16 words)
//   pa[c] = {u0,u1,v0,v1} after pl32_swap(u0=W[h][4(c&1)],   v0=W[h][4(c&1)+2])
//                               pl32_swap(u1=W[h][4(c&1)+1], v1=W[h][4(c&1)+3])
//   (h = c>>1; verified elementwise: lane5/pa[1].w0 = kv16,17; lane37 = 24,25)
// Row-sum: single shfl_xor(lp,32). LDS ~24.3 KB -> 4 blocks/CU resident.
// ---------------------------------------------------------------------------
__global__ __launch_bounds__(128) void flash_attn(
    const u16* __restrict__ Q, const u16* __restrict__ K, const u16* __restrict__ V,
    const int* __restrict__ Mask, u16* __restrict__ O)
{
  __align__(16) __shared__ u16 Ks[2][64 * 64];
  __align__(16) __shared__ u16 Vt[64 * 64];
  __align__(16) __shared__ int Ms[64];
  __shared__ int Wok[2];

  const int qt = blockIdx.x;
  const int bh = blockIdx.y;
  const int b = bh >> 4, h = bh & 15;
  const int tid = threadIdx.x;
  const int lane = tid & 63, wv = tid >> 6;
  const int H = lane >> 5, lq = lane & 31;

  const size_t baseQ  = (((size_t)b * 16 + h) * 2048 + (size_t)qt * 64) * 64;
  const size_t baseKV = ((size_t)b * 16 + h) * 2048 * 64;  // V is [B,H,D,S]

  {
    int la = 1;
#pragma unroll
    for (int i = 0; i < 16; ++i) la &= Mask[b * 2048 + tid * 16 + i];
    int wall = __all(la != 0);
    if (lane == 0) Wok[wv] = wall;
  }

  // Q fragments (B-operand): rows q = qt*64 + wv*32 + lq, d = 16c + 8H + j
  short8 qf[4];
  {
    const u16* qb = Q + baseQ + (size_t)(wv * 32 + lq) * 64 + H * 8;
#pragma unroll
    for (int c = 0; c < 4; ++c)
      qf[c] = *(const short8*)(qb + c * 16);
  }

  const u16* kg[4]; const u16* vg[4];
  int lo[4];
#pragma unroll
  for (int t = 0; t < 4; ++t) {
    int s = tid + t * 128;                  // 16B-slot 0..511 of the 8KB tile
    int row = s >> 3, ch = (s & 7) ^ (row & 7);
    kg[t] = K + baseKV + (size_t)row * 64 + ch * 8;
    vg[t] = V + baseKV + (size_t)row * 2048 + ch * 8;   // row = d for V
    lo[t] = ((tid & 64) + t * 128) * 8;     // wave-uniform base (u16 units)
  }

  // prologue: K tile 0 -> Ks[0]
#pragma unroll
  for (int t = 0; t < 4; ++t)
    __builtin_amdgcn_global_load_lds((const AS_GLOBAL unsigned int*)kg[t],
                                     (AS_LDS unsigned int*)(&Ks[0][0] + lo[t]), 16, 0, 0);

  __syncthreads();
  const bool maskall = Wok[0] && Wok[1];

  floatx16 oacc0 = {}, oacc1 = {};
  float lp = 0.f;

  int buf = 0;
#pragma unroll 2
  for (int kv0 = 0; kv0 < 2048; kv0 += 64) {
    // V(kv0) -> Vt (single-buffered; end-of-prev-iter barrier protects it)
#pragma unroll
    for (int t = 0; t < 4; ++t)
      __builtin_amdgcn_global_load_lds((const AS_GLOBAL unsigned int*)(vg[t] + kv0),
                                       (AS_LDS unsigned int*)(Vt + lo[t]), 16, 0, 0);
    // K(kv0+64) -> Ks[buf^1] (dummy wrap to tile 0 on last iter)
    const int nxt = (kv0 + 64) & 2047;
#pragma unroll
    for (int t = 0; t < 4; ++t)
      __builtin_amdgcn_global_load_lds((const AS_GLOBAL unsigned int*)(kg[t] + (size_t)nxt * 64),
                                       (AS_LDS unsigned int*)(&Ks[buf ^ 1][0] + lo[t]), 16, 0, 0);
    if (!maskall && tid < 64) Ms[tid] = Mask[b * 2048 + kv0 + tid];
    // K(kv0) landed (8 oldest done); 4V + 4K-prefetch stay in flight.
    __asm__ __volatile__("s_waitcnt vmcnt(8) lgkmcnt(0)\n\ts_barrier" ::: "memory");

    const u16* Kc = &Ks[buf][0];
    floatx16 a0 = {}, a1 = {};
    __builtin_amdgcn_s_setprio(1);
#pragma unroll
    for (int c = 0; c < 4; ++c) {
      short8 kb = *(const short8*)(Kc + lq * 64 + (((2 * c + H) ^ (lq & 7)) << 3));
      a0 = __builtin_amdgcn_mfma_f32_32x32x16_bf16(kb, qf[c], a0, 0, 0, 0);
    }
#pragma unroll
    for (int c = 0; c < 4; ++c) {
      int rr = 32 + lq;
      short8 kb = *(const short8*)(Kc + rr * 64 + (((2 * c + H) ^ (lq & 7)) << 3));
      a1 = __builtin_amdgcn_mfma_f32_32x32x16_bf16(kb, qf[c], a1, 0, 0, 0);
    }
    __builtin_amdgcn_s_setprio(0);

    float sv0[16], sv1[16];
#pragma unroll
    for (int r = 0; r < 16; ++r) { sv0[r] = a0[r]; sv1[r] = a1[r]; }
    if (!maskall) {
#pragma unroll
      for (int r = 0; r < 16; ++r) {
        int ko = (r & 3) + 8 * (r >> 2) + 4 * H;
        if (Ms[ko] == 0)      sv0[r] = -1.0e30f;
        if (Ms[32 + ko] == 0) sv1[r] = -1.0e30f;
      }
    }
#pragma unroll
    for (int r = 0; r < 16; ++r) {
      float p0 = __builtin_amdgcn_exp2f(sv0[r]);
      float p1 = __builtin_amdgcn_exp2f(sv1[r]);
      sv0[r] = p0; sv1[r] = p1;
      lp += p0 + p1;
    }

    // ---- in-register P transpose (T12 @ 32x32) ----
    unsigned int Wd0[8], Wd1[8];
#pragma unroll
    for (int i = 0; i < 8; ++i) {
      Wd0[i] = cvtpk_bf16(sv0[2 * i], sv0[2 * i + 1]);
      Wd1[i] = cvtpk_bf16(sv1[2 * i], sv1[2 * i + 1]);
    }
    short8 pa[4];
#define MAKE_PA(dst_, Wsrc_, base_) do {                                       \
    unsigned int u0 = Wsrc_[base_],     u1 = Wsrc_[(base_) + 1];               \
    unsigned int v0 = Wsrc_[(base_) + 2], v1 = Wsrc_[(base_) + 3];             \
    pl32_swap(u0, v0); pl32_swap(u1, v1);                                      \
    uint4v pw; pw[0] = u0; pw[1] = u1; pw[2] = v0; pw[3] = v1;                 \
    dst_ = __builtin_bit_cast(short8, pw);                                     \
  } while (0)
    MAKE_PA(pa[0], Wd0, 0);
    MAKE_PA(pa[1], Wd0, 4);
    MAKE_PA(pa[2], Wd1, 0);
    MAKE_PA(pa[3], Wd1, 4);
#undef MAKE_PA

    // V(kv0) landed; 4 K-prefetch stay in flight.
    __asm__ __volatile__("s_waitcnt vmcnt(4)\n\ts_barrier" ::: "memory");

    __builtin_amdgcn_s_setprio(1);
#pragma unroll
    for (int c = 0; c < 4; ++c) {
      short8 vb = *(const short8*)(Vt + lq * 64 + (((2 * c + H) ^ (lq & 7)) << 3));
      oacc0 = __builtin_amdgcn_mfma_f32_32x32x16_bf16(pa[c], vb, oacc0, 0, 0, 0);
    }
#pragma unroll
    for (int c = 0; c < 4; ++c) {
      int rr = 32 + lq;
      short8 vb = *(const short8*)(Vt + rr * 64 + (((2 * c + H) ^ (lq & 7)) << 3));
      oacc1 = __builtin_amdgcn_mfma_f32_32x32x16_bf16(pa[c], vb, oacc1, 0, 0, 0);
    }
    __builtin_amdgcn_s_setprio(0);

    // all waves done reading Ks[buf] + Vt -> safe to overwrite next iter
    __asm__ __volatile__("s_barrier" ::: "memory");
    buf ^= 1;
  }
  // drain dummy prefetch before epilogue / endpgm (LDS-dealloc hazard)
  __asm__ __volatile__("s_waitcnt vmcnt(0)" ::: "memory");

  // full row-sum for q = lq (H halves hold complementary kv sets)
  float l = lp + __shfl_xor(lp, 32);
  float inv = (l > 0.f) ? 1.0f / l : 0.f;

#pragma unroll
  for (int r = 0; r < 16; ++r) {
    int qo = (r & 3) + 8 * (r >> 2) + 4 * H;
    float ivr = __shfl(inv, qo);           // inv lives at lane qo (q-col = qo)
    int q = qt * 64 + wv * 32 + qo;
    size_t orow = ((size_t)b * 2048 + q) * 1024 + (size_t)h * 64;
    O[orow + lq]      = f2bf_fast(oacc0[r] * ivr);
    O[orow + 32 + lq] = f2bf_fast(oacc1[r] * ivr);
  }
}

// ---------------------------------------------------------------------------
extern "C" void kernel_launch(void* const* d_in, const int* in_sizes, int n_in,
                              void* d_out, int out_size, void* d_ws, size_t ws_size,
                              hipStream_t stream) {
  const void* q_in = d_in[0];
  const void* k_in = d_in[1];
  const void* v_in = d_in[2];
  const int* mask = (const int*)d_in[3];
  const void* Wq = d_in[4];  const void* bq = d_in[5];
  const void* Wk = d_in[6];  const void* bk = d_in[7];
  const void* Wv = d_in[8];  const void* bv = d_in[9];
  const void* Wo = d_in[10]; const void* bo = d_in[11];

  const size_t NTOK = (size_t)2 * 2048 * 1024;   // 4,194,304
  const size_t NW   = (size_t)1024 * 1024;       // 1,048,576

  if (ws_size >= (size_t)67108864) {
    u16* CXq = (u16*)d_ws;
    u16* CXk = CXq + NTOK;
    u16* CXv = CXk + NTOK;
    u16* CWq = CXv + NTOK;
    u16* CWk = CWq + NW;
    u16* CWv = CWk + NW;
    u16* CWo = CWv + NW;
    u16* Qp  = CWo + NW;
    u16* Kp  = Qp + NTOK;
    u16* Vp  = Kp + NTOK;   // [B,H,D,S]
    u16* Ao  = Vp + NTOK;

    cvt7<<<dim3(1024, 7), 256, 0, stream>>>(q_in, k_in, v_in, Wq, Wk, Wv, Wo,
                                            CXq, CXk, CXv, CWq, CWk, CWv, CWo);
    qkv_gemm_bf16<<<dim3(32, 8, 3), 256, 0, stream>>>(CXq, CXk, CXv,
                                                      CWq, CWk, CWv,
                                                      bq, bk, bv, Qp, Kp, Vp);
    flash_attn<<<dim3(32, 32), 128, 0, stream>>>(Qp, Kp, Vp, mask, Ao);
    out_gemm_bf16<<<dim3(32, 8), 256, 0, stream>>>(Ao, CWo, bo, (float*)d_out);
  } else {
    u16* Qp = (u16*)d_ws;
    u16* Kp = Qp + NTOK;
    u16* Vp = Kp + NTOK;    // [B,H,D,S]
    u16* Ao  = Vp + NTOK;

    qkv_gemm_cvt<<<dim3(8, 32, 3), 256, 0, stream>>>(q_in, k_in, v_in,
                                                     Wq, Wk, Wv, bq, bk, bv,
                                                     Qp, Kp, Vp);
    flash_attn<<<dim3(32, 32), 128, 0, stream>>>(Qp, Kp, Vp, mask, Ao);
    out_gemm_cvt<<<dim3(8, 32), 256, 0, stream>>>(Ao, Wo, bo, (float*)d_out);
  }
}